// Round 7
// baseline (346.471 us; speedup 1.0000x reference)
//
#include <hip/hip_runtime.h>
#include <math.h>

#define NN 4096
#define DD 512
#define INV_TAU 5.0f
#define EPSV 1e-15f

typedef unsigned short u16;
typedef __attribute__((ext_vector_type(8))) short short8;
typedef __attribute__((ext_vector_type(4))) float f32x4;

__device__ __forceinline__ void gld16(const void* g, void* l) {
  __builtin_amdgcn_global_load_lds(
      (const __attribute__((address_space(1))) unsigned int*)g,
      (__attribute__((address_space(3))) unsigned int*)l, 16, 0, 0);
}

__device__ __forceinline__ float bf2f(u16 u) {
  return __uint_as_float(((unsigned)u) << 16);
}
__device__ __forceinline__ u16 f2bf(float x) {  // RNE
  unsigned u = __float_as_uint(x);
  u += 0x7fff + ((u >> 16) & 1);
  return (u16)(u >> 16);
}

__device__ __forceinline__ float wave_sum(float v) {
#pragma unroll
  for (int o = 32; o > 0; o >>= 1) v += __shfl_down(v, o, 64);
  return v;
}

__device__ __forceinline__ float invnorm(float n) {
  return 1.f / fmaxf(sqrtf(n), 1e-12f);
}

// ---- prep: z1/z2 fp32 -> bf16 + column means; weights fp32 -> bf16 ----------
// y=2 blocks also zero the zbf/norm2 accumulation region (replaces memset).
__global__ __launch_bounds__(256) void prep(
    const float* __restrict__ z1, const float* __restrict__ z2,
    const float* __restrict__ lw1, const float* __restrict__ lw2,
    u16* __restrict__ Ab, u16* __restrict__ Wb, float* __restrict__ s1,
    float* __restrict__ s2, float* __restrict__ zbf) {
  const int tid = threadIdx.x;
  if (blockIdx.y == 2) {
#pragma unroll
    for (int k = 0; k < 8; ++k) {
      const int idx = blockIdx.x * 256 + tid + k * 16384;
      const float* s = (idx < 65536) ? &lw1[(size_t)idx * 4]
                                     : &lw2[(size_t)(idx - 65536) * 4];
      float4 v = *(const float4*)s;
      unsigned long long pk = (unsigned long long)f2bf(v.x) |
                              ((unsigned long long)f2bf(v.y) << 16) |
                              ((unsigned long long)f2bf(v.z) << 32) |
                              ((unsigned long long)f2bf(v.w) << 48);
      *(unsigned long long*)&Wb[(size_t)idx * 4] = pk;
    }
    const int zidx = blockIdx.x * 256 + tid;  // zero zbf(8NN)+norm2(2NN)
    if (zidx < 10240)
      *(float4*)&zbf[(size_t)zidx * 4] = make_float4(0.f, 0.f, 0.f, 0.f);
    return;
  }
  const float* z = blockIdx.y ? z2 : z1;
  u16* dst = Ab + (size_t)blockIdx.y * ((size_t)NN * DD);
  float* sdst = blockIdx.y ? s2 : s1;
  const int col4 = tid & 127;
  const int rg = tid >> 7;
  const int r0 = blockIdx.x * 64;
  float4 acc = make_float4(0.f, 0.f, 0.f, 0.f);
#pragma unroll 4
  for (int k = 0; k < 32; ++k) {
    const int r = r0 + rg + k * 2;
    float4 v = *(const float4*)&z[(size_t)r * DD + col4 * 4];
    acc.x += v.x; acc.y += v.y; acc.z += v.z; acc.w += v.w;
    unsigned long long pk = (unsigned long long)f2bf(v.x) |
                            ((unsigned long long)f2bf(v.y) << 16) |
                            ((unsigned long long)f2bf(v.z) << 32) |
                            ((unsigned long long)f2bf(v.w) << 48);
    *(unsigned long long*)&dst[(size_t)r * DD + col4 * 4] = pk;
  }
  const float inv = 1.f / NN;
  atomicAdd(&sdst[col4 * 4 + 0], acc.x * inv);
  atomicAdd(&sdst[col4 * 4 + 1], acc.y * inv);
  atomicAdd(&sdst[col4 * 4 + 2], acc.z * inv);
  atomicAdd(&sdst[col4 * 4 + 3], acc.w * inv);
}

// ------------- MFMA NT GEMM, pipelined: out = act(A@Bw^T + bias) -------------
template <int ACT, int NRM>
__global__ __launch_bounds__(256) void gemm_mfma(
    const u16* __restrict__ A, const u16* __restrict__ Bw,
    const float* __restrict__ bias, const float* __restrict__ alpha_p,
    u16* __restrict__ out, float* __restrict__ norm2) {
  __shared__ __align__(16) u16 sA[2][128 * 32], sB[2][64 * 32];
  const int tid = threadIdx.x, w = tid >> 6, lane = tid & 63;
  const int rq = lane >> 2, cq = (lane & 3) * 8;
  const int quad = lane >> 4, m16 = lane & 15;
  const int wi = w >> 1, wj = w & 1;
  const int i0 = blockIdx.y * 128, j0 = blockIdx.x * 64;
  const u16* Apan = A + (size_t)blockIdx.z * ((size_t)NN * DD);
  u16* ob = out + (size_t)blockIdx.z * ((size_t)NN * DD);
  float* npan = norm2 + (size_t)blockIdx.z * NN;
  const bool st = (w < 3);
  const u16* gs = (w == 2) ? Bw : Apan;
  const int gr0 = (w == 2) ? (j0 + rq) : (i0 + (w == 1 ? 64 : 0) + rq);
  u16* lb0 = (w == 2) ? sB[0] : &sA[0][(w == 1 ? 64 : 0) * 32];
  u16* lb1 = (w == 2) ? sB[1] : &sA[1][(w == 1 ? 64 : 0) * 32];
  if (st) {
#pragma unroll
    for (int rr = 0; rr < 64; rr += 16)
      gld16(&gs[(size_t)(gr0 + rr) * DD + cq], lb0 + rr * 32);
  }
  f32x4 acc[4][2] = {};
  for (int kc = 0; kc < 16; ++kc) {
    __syncthreads();
    if (kc < 15 && st) {
      const int kn = (kc + 1) * 32;
      u16* d = (kc & 1) ? lb0 : lb1;
#pragma unroll
      for (int rr = 0; rr < 64; rr += 16)
        gld16(&gs[(size_t)(gr0 + rr) * DD + kn + cq], d + rr * 32);
    }
    const u16* As = sA[kc & 1];
    const u16* Bs = sB[kc & 1];
    short8 bj[2];
#pragma unroll
    for (int sj = 0; sj < 2; ++sj)
      bj[sj] = *(const short8*)&Bs[(wj * 32 + sj * 16 + m16) * 32 + quad * 8];
#pragma unroll
    for (int si = 0; si < 4; ++si) {
      short8 ai = *(const short8*)&As[(wi * 64 + si * 16 + m16) * 32 + quad * 8];
#pragma unroll
      for (int sj = 0; sj < 2; ++sj)
        acc[si][sj] = __builtin_amdgcn_mfma_f32_16x16x32_bf16(
            ai, bj[sj], acc[si][sj], 0, 0, 0);
    }
  }
  const float al = ACT ? alpha_p[0] : 0.f;
  float ssq[4][4] = {};
#pragma unroll
  for (int si = 0; si < 4; ++si)
#pragma unroll
    for (int sj = 0; sj < 2; ++sj) {
      const int col = j0 + wj * 32 + sj * 16 + m16;
      const float bv = bias[col];
#pragma unroll
      for (int r = 0; r < 4; ++r) {
        const int row = i0 + wi * 64 + si * 16 + quad * 4 + r;
        float x = acc[si][sj][r] + bv;
        if (ACT) x = (x >= 0.f) ? x : al * x;
        const u16 xb = f2bf(x);
        ob[(size_t)row * DD + col] = xb;
        if (NRM) {
          const float xf = bf2f(xb);
          ssq[si][r] += xf * xf;
        }
      }
    }
  if (NRM) {
#pragma unroll
    for (int si = 0; si < 4; ++si)
#pragma unroll
      for (int r = 0; r < 4; ++r) {
        float s = ssq[si][r];
        s += __shfl_xor(s, 1, 64);
        s += __shfl_xor(s, 2, 64);
        s += __shfl_xor(s, 4, 64);
        s += __shfl_xor(s, 8, 64);
        if (m16 == 0)
          atomicAdd(&npan[i0 + wi * 64 + si * 16 + quad * 4 + r], s);
      }
  }
}

// ---- triangular fused similarity, 128x128 tiles, 512 thr (8 waves) ----------
// blocks (bi<=bj). Upper tile: S11,S12,S22 + mirror S12 via alo=mfma(aj,bi)
// (fragment reuse, no extra LDS reads). S11/S22 mirror stats via symmetry.
// zb: [r11s, r11m, r12s, r12m, c12s, c12m, c22s, c22m] x NN.
__global__ __launch_bounds__(512) void sim_tri(
    const u16* __restrict__ na, const u16* __restrict__ nb,
    const float* __restrict__ n2A, const float* __restrict__ n2B,
    const int* __restrict__ mask, float* __restrict__ zb) {
  __shared__ __align__(16) u16 sP[2][4][128 * 32];  // 64 KiB
  const int tid = threadIdx.x, w = tid >> 6, lane = tid & 63;
  const int rq = lane >> 2, cq = (lane & 3) * 8;
  const int quad = lane >> 4, m16 = lane & 15;
  const int ig = w & 3, jh = w >> 2;
  // ---- triangle decode: b -> (bi<=bj), 32 tiles/dim; start(x)=x*(65-x)/2 ----
  const int b = blockIdx.x;
  int bi = (int)((65.0f - sqrtf(4225.0f - 8.0f * (float)b)) * 0.5f);
  if (bi < 0) bi = 0;
  if (bi > 31) bi = 31;
  while (bi * (65 - bi) / 2 > b) --bi;
  while ((bi + 1) * (64 - bi) / 2 <= b) ++bi;
  const int bj = bi + (b - bi * (65 - bi) / 2);
  const int i0 = bi * 128, j0 = bj * 128;
  const bool offd = (bi != bj);
  // staging: panel p = w>>1 (0 na@I, 1 nb@I, 2 na@J, 3 nb@J), rows rh..rh+63
  const int p = w >> 1, rh = (w & 1) * 64;
  const u16* gs = (p & 1) ? nb : na;
  const int gr0 = ((p < 2) ? i0 : j0) + rh + rq;
  u16* lb0 = &sP[0][p][rh * 32];
  u16* lb1 = &sP[1][p][rh * 32];
#pragma unroll
  for (int rr = 0; rr < 64; rr += 16)
    gld16(&gs[(size_t)(gr0 + rr) * DD + cq], lb0 + rr * 32);
  f32x4 a11[2][4] = {}, a12[2][4] = {}, a22[2][4] = {}, alo[4][2] = {};
  for (int kc = 0; kc < 16; ++kc) {
    __syncthreads();
    if (kc < 15) {
      const int kn = (kc + 1) * 32;
      u16* d = (kc & 1) ? lb0 : lb1;
#pragma unroll
      for (int rr = 0; rr < 64; rr += 16)
        gld16(&gs[(size_t)(gr0 + rr) * DD + kn + cq], d + rr * 32);
    }
    const u16* Ai = sP[kc & 1][0];
    const u16* Bi = sP[kc & 1][1];
    const u16* Aj = sP[kc & 1][2];
    const u16* Bj = sP[kc & 1][3];
    short8 ai[2], bi2[2], aj[4], bj2[4];
#pragma unroll
    for (int s = 0; s < 2; ++s) {
      ai[s] = *(const short8*)&Ai[(ig * 32 + s * 16 + m16) * 32 + quad * 8];
      bi2[s] = *(const short8*)&Bi[(ig * 32 + s * 16 + m16) * 32 + quad * 8];
    }
#pragma unroll
    for (int sj = 0; sj < 4; ++sj) {
      aj[sj] = *(const short8*)&Aj[(jh * 64 + sj * 16 + m16) * 32 + quad * 8];
      bj2[sj] = *(const short8*)&Bj[(jh * 64 + sj * 16 + m16) * 32 + quad * 8];
    }
#pragma unroll
    for (int si = 0; si < 2; ++si)
#pragma unroll
      for (int sj = 0; sj < 4; ++sj) {
        a11[si][sj] = __builtin_amdgcn_mfma_f32_16x16x32_bf16(ai[si], aj[sj], a11[si][sj], 0, 0, 0);
        a12[si][sj] = __builtin_amdgcn_mfma_f32_16x16x32_bf16(ai[si], bj2[sj], a12[si][sj], 0, 0, 0);
        a22[si][sj] = __builtin_amdgcn_mfma_f32_16x16x32_bf16(bi2[si], bj2[sj], a22[si][sj], 0, 0, 0);
      }
    if (offd) {
#pragma unroll
      for (int sj = 0; sj < 4; ++sj)
#pragma unroll
        for (int si = 0; si < 2; ++si)
          alo[sj][si] = __builtin_amdgcn_mfma_f32_16x16x32_bf16(aj[sj], bi2[si], alo[sj][si], 0, 0, 0);
    }
  }
  __syncthreads();
  // overlay sP[0] (32 KB): mirror-mask bytes [128][132] + 4x [4][128] red bufs
  unsigned char* smT = (unsigned char*)&sP[0][0][0];  // 16896 B
  float* red = (float*)(smT + 16896);                 // 2048 floats
  float* rredI = red;                                 // [4][128] -> zb[0..3]+i0
  float* credJ = red + 512;                           // [4][128] -> zb[4..7]+j0
  float* rredJ = red + 1024;                          // [4][128] -> zb[0..3]+j0
  float* credI = red + 1536;                          // [4][128] -> zb[4..7]+i0
  if (offd) {
#pragma unroll
    for (int it = 0; it < 8; ++it) {
      const int linear = tid + it * 512;  // int4 idx over 128x32
      const int r = linear >> 5, c4 = (linear & 31) * 4;
      const int4 v = *(const int4*)&mask[(size_t)(j0 + r) * NN + i0 + c4];
      smT[r * 132 + c4 + 0] = (unsigned char)v.x;
      smT[r * 132 + c4 + 1] = (unsigned char)v.y;
      smT[r * 132 + c4 + 2] = (unsigned char)v.z;
      smT[r * 132 + c4 + 3] = (unsigned char)v.w;
    }
  }
  red[tid] = 0.f; red[tid + 512] = 0.f;
  red[tid + 1024] = 0.f; red[tid + 1536] = 0.f;
  __syncthreads();
  // norm factors
  float iAr[2][4], iBr[2][4], iBcI[2], iAc[4], iBc[4], jAr[4][4];
#pragma unroll
  for (int si = 0; si < 2; ++si) {
    const int ri = i0 + ig * 32 + si * 16 + quad * 4;
    float4 a4 = *(const float4*)&n2A[ri];
    float4 b4 = *(const float4*)&n2B[ri];
    iAr[si][0] = invnorm(a4.x); iAr[si][1] = invnorm(a4.y);
    iAr[si][2] = invnorm(a4.z); iAr[si][3] = invnorm(a4.w);
    iBr[si][0] = invnorm(b4.x); iBr[si][1] = invnorm(b4.y);
    iBr[si][2] = invnorm(b4.z); iBr[si][3] = invnorm(b4.w);
    iBcI[si] = invnorm(n2B[i0 + ig * 32 + si * 16 + m16]);
  }
#pragma unroll
  for (int sj = 0; sj < 4; ++sj) {
    iAc[sj] = invnorm(n2A[j0 + jh * 64 + sj * 16 + m16]);
    iBc[sj] = invnorm(n2B[j0 + jh * 64 + sj * 16 + m16]);
    float4 c4 = *(const float4*)&n2A[j0 + jh * 64 + sj * 16 + quad * 4];
    jAr[sj][0] = invnorm(c4.x); jAr[sj][1] = invnorm(c4.y);
    jAr[sj][2] = invnorm(c4.z); jAr[sj][3] = invnorm(c4.w);
  }
  float cs12[4] = {}, cm12[4] = {}, cs22[4] = {}, cm22[4] = {};
  float ms11[4] = {}, mm11[4] = {};
#pragma unroll
  for (int si = 0; si < 2; ++si) {
    float rs11[4] = {}, rm11[4] = {}, rs12[4] = {}, rm12[4] = {};
    float xs22[4] = {}, xm22[4] = {};
    const int il0 = ig * 32 + si * 16 + quad * 4;
#pragma unroll
    for (int sj = 0; sj < 4; ++sj) {
      const int jl = jh * 64 + sj * 16 + m16;
      const int gj = j0 + jl;
#pragma unroll
      for (int r = 0; r < 4; ++r) {
        const int il = il0 + r;
        const float mv = (float)mask[(size_t)(i0 + il) * NN + gj];
        const float e11 = __expf(a11[si][sj][r] * iAr[si][r] * iAc[sj] * INV_TAU);
        const float e12 = __expf(a12[si][sj][r] * iAr[si][r] * iBc[sj] * INV_TAU);
        const float e22 = __expf(a22[si][sj][r] * iBr[si][r] * iBc[sj] * INV_TAU);
        rs11[r] += e11; rm11[r] += e11 * mv;
        rs12[r] += e12; rm12[r] += e12 * mv;
        cs12[sj] += e12; cm12[sj] += e12 * mv;
        cs22[sj] += e22; cm22[sj] += e22 * mv;
        if (offd) {
          const float mt = (float)smT[jl * 132 + il];
          ms11[sj] += e11; mm11[sj] += e11 * mt;
          xs22[r] += e22; xm22[r] += e22 * mt;
        }
      }
    }
#pragma unroll
    for (int r = 0; r < 4; ++r) {
      float v0 = rs11[r], v1 = rm11[r], v2 = rs12[r], v3 = rm12[r];
      float v4 = xs22[r], v5 = xm22[r];
#pragma unroll
      for (int o = 1; o < 16; o <<= 1) {
        v0 += __shfl_xor(v0, o, 64); v1 += __shfl_xor(v1, o, 64);
        v2 += __shfl_xor(v2, o, 64); v3 += __shfl_xor(v3, o, 64);
        v4 += __shfl_xor(v4, o, 64); v5 += __shfl_xor(v5, o, 64);
      }
      if (m16 == 0) {
        const int il = il0 + r;
        atomicAdd(&rredI[0 * 128 + il], v0);
        atomicAdd(&rredI[1 * 128 + il], v1);
        atomicAdd(&rredI[2 * 128 + il], v2);
        atomicAdd(&rredI[3 * 128 + il], v3);
        if (offd) {
          atomicAdd(&credI[2 * 128 + il], v4);
          atomicAdd(&credI[3 * 128 + il], v5);
        }
      }
    }
  }
  // mirror S12 (rows J, cols I)
  float cs12I[2] = {}, cm12I[2] = {};
  if (offd) {
#pragma unroll
    for (int sj = 0; sj < 4; ++sj) {
      float rsJ[4] = {}, rmJ[4] = {};
      const int jr0 = jh * 64 + sj * 16 + quad * 4;
#pragma unroll
      for (int si = 0; si < 2; ++si) {
        const int ic = ig * 32 + si * 16 + m16;
#pragma unroll
        for (int r = 0; r < 4; ++r) {
          const float e12l = __expf(alo[sj][si][r] * jAr[sj][r] * iBcI[si] * INV_TAU);
          const float mt2 = (float)smT[(jr0 + r) * 132 + ic];
          rsJ[r] += e12l; rmJ[r] += e12l * mt2;
          cs12I[si] += e12l; cm12I[si] += e12l * mt2;
        }
      }
#pragma unroll
      for (int r = 0; r < 4; ++r) {
        float v0 = rsJ[r], v1 = rmJ[r];
#pragma unroll
        for (int o = 1; o < 16; o <<= 1) {
          v0 += __shfl_xor(v0, o, 64);
          v1 += __shfl_xor(v1, o, 64);
        }
        if (m16 == 0) {
          atomicAdd(&rredJ[2 * 128 + jr0 + r], v0);
          atomicAdd(&rredJ[3 * 128 + jr0 + r], v1);
        }
      }
    }
  }
  // column reductions over quads (xor 16, 32)
#pragma unroll
  for (int sj = 0; sj < 4; ++sj) {
    float v0 = cs12[sj], v1 = cm12[sj], v2 = cs22[sj], v3 = cm22[sj];
    float v4 = ms11[sj], v5 = mm11[sj];
    v0 += __shfl_xor(v0, 16, 64); v0 += __shfl_xor(v0, 32, 64);
    v1 += __shfl_xor(v1, 16, 64); v1 += __shfl_xor(v1, 32, 64);
    v2 += __shfl_xor(v2, 16, 64); v2 += __shfl_xor(v2, 32, 64);
    v3 += __shfl_xor(v3, 16, 64); v3 += __shfl_xor(v3, 32, 64);
    v4 += __shfl_xor(v4, 16, 64); v4 += __shfl_xor(v4, 32, 64);
    v5 += __shfl_xor(v5, 16, 64); v5 += __shfl_xor(v5, 32, 64);
    if (lane < 16) {
      const int jl = jh * 64 + sj * 16 + lane;
      atomicAdd(&credJ[0 * 128 + jl], v0);
      atomicAdd(&credJ[1 * 128 + jl], v1);
      atomicAdd(&credJ[2 * 128 + jl], v2);
      atomicAdd(&credJ[3 * 128 + jl], v3);
      if (offd) {
        atomicAdd(&rredJ[0 * 128 + jl], v4);
        atomicAdd(&rredJ[1 * 128 + jl], v5);
      }
    }
  }
  if (offd) {
#pragma unroll
    for (int si = 0; si < 2; ++si) {
      float v6 = cs12I[si], v7 = cm12I[si];
      v6 += __shfl_xor(v6, 16, 64); v6 += __shfl_xor(v6, 32, 64);
      v7 += __shfl_xor(v7, 16, 64); v7 += __shfl_xor(v7, 32, 64);
      if (lane < 16) {
        const int ic = ig * 32 + si * 16 + lane;
        atomicAdd(&credI[0 * 128 + ic], v6);
        atomicAdd(&credI[1 * 128 + ic], v7);
      }
    }
  }
  __syncthreads();
  const int arr = tid >> 7, t = tid & 127;
  if (arr == 0) {
#pragma unroll
    for (int q = 0; q < 4; ++q)
      atomicAdd(&zb[q * NN + i0 + t], rredI[q * 128 + t]);
  } else if (arr == 1) {
#pragma unroll
    for (int q = 0; q < 4; ++q)
      atomicAdd(&zb[(4 + q) * NN + j0 + t], credJ[q * 128 + t]);
  } else if (arr == 2 && offd) {
#pragma unroll
    for (int q = 0; q < 4; ++q)
      atomicAdd(&zb[q * NN + j0 + t], rredJ[q * 128 + t]);
  } else if (arr == 3 && offd) {
#pragma unroll
    for (int q = 0; q < 4; ++q)
      atomicAdd(&zb[(4 + q) * NN + i0 + t], credI[q * 128 + t]);
  }
}

// ---------------- paired D x D matvec, one wave per output row ---------------
__global__ __launch_bounds__(256) void matvec2(
    const float* __restrict__ M, const float* __restrict__ x1,
    const float* __restrict__ x2, const float* __restrict__ bias,
    const float* __restrict__ alpha_p, int act, float* __restrict__ y1,
    float* __restrict__ y2) {
  const float* x = blockIdx.y ? x2 : x1;
  float* y = blockIdx.y ? y2 : y1;
  const int row = (blockIdx.x * 256 + threadIdx.x) >> 6;
  const int lane = threadIdx.x & 63;
  float acc = 0.f;
#pragma unroll
  for (int t = 0; t < 8; ++t)
    acc = fmaf(M[(size_t)row * DD + lane + 64 * t], x[lane + 64 * t], acc);
  acc = wave_sum(acc);
  if (lane == 0) {
    if (bias) acc += bias[row];
    if (act) { const float al = alpha_p[0]; acc = (acc >= 0.f) ? acc : al * acc; }
    y[row] = acc;
  }
}

// ------- finalize: logsig (512 blocks) + local_fin (16 blocks) + combine -----
__global__ __launch_bounds__(256) void finalize(
    const float* __restrict__ zb, const u16* __restrict__ zb16,
    const float* __restrict__ sm1, const float* __restrict__ sm2,
    float* __restrict__ scal, float* __restrict__ out) {
  const int b = blockIdx.x;
  const int tid = threadIdx.x;
  if (b < 512) {
    const int ch = b >> 8, sub = b & 255;
    const u16* z = zb16 + (size_t)ch * ((size_t)NN * DD);
    const float* sp = ch ? sm2 : sm1;
    const float* sn = ch ? sm1 : sm2;
    const int lane = tid & 63, wv = tid >> 6;
    float sp8[8], sn8[8];
#pragma unroll
    for (int k = 0; k < 8; ++k) {
      sp8[k] = sp[lane * 8 + k];
      sn8[k] = sn[lane * 8 + k];
    }
    float accP = 0.f, accN = 0.f;
#pragma unroll
    for (int rr = 0; rr < 4; ++rr) {
      const int row = sub * 16 + wv * 4 + rr;
      short8 v = *(const short8*)&z[(size_t)row * DD + lane * 8];
      float dp = 0.f, dn = 0.f;
#pragma unroll
      for (int k = 0; k < 8; ++k) {
        const float f = bf2f(((const u16*)&v)[k]);
        dp = fmaf(f, sp8[k], dp);
        dn = fmaf(f, sn8[k], dn);
      }
      dp = wave_sum(dp);
      dn = wave_sum(dn);
      if (lane == 0) {
        accP += -logf(1.f / (1.f + __expf(-dp)) + EPSV);
        accN += -logf(1.f - 1.f / (1.f + __expf(-dn)) + EPSV);
      }
    }
    if (lane == 0) {
      atomicAdd(&scal[ch ? 4 : 2], accP);
      atomicAdd(&scal[ch ? 3 : 5], accN);
    }
  } else {
    const int i = (b - 512) * 256 + tid;
    const float r11 = zb[i], r11m = zb[NN + i];
    const float r12 = zb[2 * NN + i], r12m = zb[3 * NN + i];
    const float c12 = zb[4 * NN + i], c12m = zb[5 * NN + i];
    const float c22 = zb[6 * NN + i], c22m = zb[7 * NN + i];
    float l1 = -logf(r12m / (r11 + r12 - r11m));
    float l2 = -logf(c12m / (c22 + c12 - c22m));
    l1 = wave_sum(l1);
    l2 = wave_sum(l2);
    __shared__ float b1[4], b2[4];
    const int lane = tid & 63, wid = tid >> 6;
    if (lane == 0) { b1[wid] = l1; b2[wid] = l2; }
    __syncthreads();
    if (tid == 0) {
      atomicAdd(&scal[0], b1[0] + b1[1] + b1[2] + b1[3]);
      atomicAdd(&scal[1], b2[0] + b2[1] + b2[2] + b2[3]);
    }
  }
  __syncthreads();
  if (tid == 0) {
    unsigned int* cnt = (unsigned int*)&scal[8];
    const unsigned old = atomicAdd(cnt, 1u);
    if (old == (unsigned)(gridDim.x - 1)) {
      const float s0 = atomicAdd(&scal[0], 0.f);
      const float s1 = atomicAdd(&scal[1], 0.f);
      const float p1 = atomicAdd(&scal[2], 0.f);
      const float n1 = atomicAdd(&scal[3], 0.f);
      const float p2 = atomicAdd(&scal[4], 0.f);
      const float n2 = atomicAdd(&scal[5], 0.f);
      const float local = 0.5f * (s0 + s1) * (1.f / NN);
      const float glob = 0.25f * (p1 + n1 + p2 + n2) * (1.f / NN);
      out[0] = 0.5f * local + 0.5f * glob;
    }
  }
}

extern "C" void kernel_launch(void* const* d_in, const int* in_sizes, int n_in,
                              void* d_out, int out_size, void* d_ws,
                              size_t ws_size, hipStream_t stream) {
  const float* z1 = (const float*)d_in[0];
  const float* z2 = (const float*)d_in[1];
  const float* lw1 = (const float*)d_in[2];
  const float* lb1 = (const float*)d_in[3];
  const float* la = (const float*)d_in[4];
  const float* lw2 = (const float*)d_in[5];
  const float* lb2 = (const float*)d_in[6];
  const float* gw1 = (const float*)d_in[7];
  const float* gb1 = (const float*)d_in[8];
  const float* ga = (const float*)d_in[9];
  const float* gw2 = (const float*)d_in[10];
  const float* gb2 = (const float*)d_in[11];
  const float* W = (const float*)d_in[12];
  const int* mask = (const int*)d_in[13];
  float* out = (float*)d_out;

  const size_t ND = (size_t)NN * DD;
  u16* W1b = (u16*)d_ws;
  u16* W2b = W1b + 512 * 512;
  u16* Ab = W1b + 2 * 512 * 512;
  u16* Pb = Ab + 2 * ND;
  u16* Hb = Pb + 2 * ND;
  float* zbf = (float*)(Hb + 2 * ND);     // 8*NN (zeroed by prep y2)
  float* norm2 = zbf + 8 * NN;            // 2*NN (zeroed by prep y2)
  float* s1 = norm2 + 2 * NN;             // memset region start
  float* s2 = s1 + DD;
  float* scal = s2 + DD;                  // [16], counter at [8]
  float* summ1 = scal + 16;
  float* summ2 = summ1 + DD;
  float* t1 = summ2 + DD;
  float* t2 = t1 + DD;
  float* hg1 = t2 + DD;
  float* hg2 = hg1 + DD;

  hipMemsetAsync(s1, 0, (2 * DD + 16) * sizeof(float), stream);

  dim3 blk(256);
  prep<<<dim3(64, 3), blk, 0, stream>>>(z1, z2, lw1, lw2, Ab, W1b, s1, s2, zbf);

  dim3 gg(8, 32, 2);
  gemm_mfma<1, 0><<<gg, blk, 0, stream>>>(Ab, W1b, lb1, la, Pb, nullptr);
  gemm_mfma<0, 1><<<gg, blk, 0, stream>>>(Pb, W2b, lb2, la, Hb, norm2);

  sim_tri<<<528, dim3(512), 0, stream>>>(Hb, Hb + ND, norm2, norm2 + NN, mask,
                                         zbf);

  matvec2<<<dim3(DD / 4, 2), blk, 0, stream>>>(gw1, s1, s2, gb1, ga, 1, t1, t2);
  matvec2<<<dim3(DD / 4, 2), blk, 0, stream>>>(gw2, t1, t2, gb2, nullptr, 0, hg1, hg2);
  matvec2<<<dim3(DD / 4, 2), blk, 0, stream>>>(W, hg1, hg2, nullptr, nullptr, 0, summ1, summ2);

  finalize<<<528, blk, 0, stream>>>(zbf, Ab, summ1, summ2, scal, out);
}

// Round 8
// 344.251 us; speedup vs baseline: 1.0064x; 1.0064x over previous
//
#include <hip/hip_runtime.h>
#include <math.h>

#define NN 4096
#define DD 512
#define INV_TAU 5.0f
#define EPSV 1e-15f

typedef unsigned short u16;
typedef __attribute__((ext_vector_type(8))) short short8;
typedef __attribute__((ext_vector_type(4))) float f32x4;

__device__ __forceinline__ void gld16(const void* g, void* l) {
  __builtin_amdgcn_global_load_lds(
      (const __attribute__((address_space(1))) unsigned int*)g,
      (__attribute__((address_space(3))) unsigned int*)l, 16, 0, 0);
}

__device__ __forceinline__ float bf2f(u16 u) {
  return __uint_as_float(((unsigned)u) << 16);
}
__device__ __forceinline__ u16 f2bf(float x) {  // RNE
  unsigned u = __float_as_uint(x);
  u += 0x7fff + ((u >> 16) & 1);
  return (u16)(u >> 16);
}

__device__ __forceinline__ float wave_sum(float v) {
#pragma unroll
  for (int o = 32; o > 0; o >>= 1) v += __shfl_down(v, o, 64);
  return v;
}

__device__ __forceinline__ float invnorm(float n) {
  return 1.f / fmaxf(sqrtf(n), 1e-12f);
}

// ---- prep: z1/z2 fp32 -> bf16 + column means; weights fp32 -> bf16 ----------
// y=2 blocks also zero the zbf/norm2 accumulation region (replaces memset).
__global__ __launch_bounds__(256) void prep(
    const float* __restrict__ z1, const float* __restrict__ z2,
    const float* __restrict__ lw1, const float* __restrict__ lw2,
    u16* __restrict__ Ab, u16* __restrict__ Wb, float* __restrict__ s1,
    float* __restrict__ s2, float* __restrict__ zbf) {
  const int tid = threadIdx.x;
  if (blockIdx.y == 2) {
#pragma unroll
    for (int k = 0; k < 8; ++k) {
      const int idx = blockIdx.x * 256 + tid + k * 16384;
      const float* s = (idx < 65536) ? &lw1[(size_t)idx * 4]
                                     : &lw2[(size_t)(idx - 65536) * 4];
      float4 v = *(const float4*)s;
      unsigned long long pk = (unsigned long long)f2bf(v.x) |
                              ((unsigned long long)f2bf(v.y) << 16) |
                              ((unsigned long long)f2bf(v.z) << 32) |
                              ((unsigned long long)f2bf(v.w) << 48);
      *(unsigned long long*)&Wb[(size_t)idx * 4] = pk;
    }
    const int zidx = blockIdx.x * 256 + tid;  // zero zbf(8NN)+norm2(2NN)
    if (zidx < 10240)
      *(float4*)&zbf[(size_t)zidx * 4] = make_float4(0.f, 0.f, 0.f, 0.f);
    return;
  }
  const float* z = blockIdx.y ? z2 : z1;
  u16* dst = Ab + (size_t)blockIdx.y * ((size_t)NN * DD);
  float* sdst = blockIdx.y ? s2 : s1;
  const int col4 = tid & 127;
  const int rg = tid >> 7;
  const int r0 = blockIdx.x * 64;
  float4 acc = make_float4(0.f, 0.f, 0.f, 0.f);
#pragma unroll 4
  for (int k = 0; k < 32; ++k) {
    const int r = r0 + rg + k * 2;
    float4 v = *(const float4*)&z[(size_t)r * DD + col4 * 4];
    acc.x += v.x; acc.y += v.y; acc.z += v.z; acc.w += v.w;
    unsigned long long pk = (unsigned long long)f2bf(v.x) |
                            ((unsigned long long)f2bf(v.y) << 16) |
                            ((unsigned long long)f2bf(v.z) << 32) |
                            ((unsigned long long)f2bf(v.w) << 48);
    *(unsigned long long*)&dst[(size_t)r * DD + col4 * 4] = pk;
  }
  const float inv = 1.f / NN;
  atomicAdd(&sdst[col4 * 4 + 0], acc.x * inv);
  atomicAdd(&sdst[col4 * 4 + 1], acc.y * inv);
  atomicAdd(&sdst[col4 * 4 + 2], acc.z * inv);
  atomicAdd(&sdst[col4 * 4 + 3], acc.w * inv);
}

// ------------- MFMA NT GEMM, pipelined: out = act(A@Bw^T + bias) -------------
template <int ACT, int NRM>
__global__ __launch_bounds__(256) void gemm_mfma(
    const u16* __restrict__ A, const u16* __restrict__ Bw,
    const float* __restrict__ bias, const float* __restrict__ alpha_p,
    u16* __restrict__ out, float* __restrict__ norm2) {
  __shared__ __align__(16) u16 sA[2][128 * 32], sB[2][64 * 32];
  const int tid = threadIdx.x, w = tid >> 6, lane = tid & 63;
  const int rq = lane >> 2, cq = (lane & 3) * 8;
  const int quad = lane >> 4, m16 = lane & 15;
  const int wi = w >> 1, wj = w & 1;
  const int i0 = blockIdx.y * 128, j0 = blockIdx.x * 64;
  const u16* Apan = A + (size_t)blockIdx.z * ((size_t)NN * DD);
  u16* ob = out + (size_t)blockIdx.z * ((size_t)NN * DD);
  float* npan = norm2 + (size_t)blockIdx.z * NN;
  const bool st = (w < 3);
  const u16* gs = (w == 2) ? Bw : Apan;
  const int gr0 = (w == 2) ? (j0 + rq) : (i0 + (w == 1 ? 64 : 0) + rq);
  u16* lb0 = (w == 2) ? sB[0] : &sA[0][(w == 1 ? 64 : 0) * 32];
  u16* lb1 = (w == 2) ? sB[1] : &sA[1][(w == 1 ? 64 : 0) * 32];
  if (st) {
#pragma unroll
    for (int rr = 0; rr < 64; rr += 16)
      gld16(&gs[(size_t)(gr0 + rr) * DD + cq], lb0 + rr * 32);
  }
  f32x4 acc[4][2] = {};
  for (int kc = 0; kc < 16; ++kc) {
    __syncthreads();
    if (kc < 15 && st) {
      const int kn = (kc + 1) * 32;
      u16* d = (kc & 1) ? lb0 : lb1;
#pragma unroll
      for (int rr = 0; rr < 64; rr += 16)
        gld16(&gs[(size_t)(gr0 + rr) * DD + kn + cq], d + rr * 32);
    }
    const u16* As = sA[kc & 1];
    const u16* Bs = sB[kc & 1];
    short8 bj[2];
#pragma unroll
    for (int sj = 0; sj < 2; ++sj)
      bj[sj] = *(const short8*)&Bs[(wj * 32 + sj * 16 + m16) * 32 + quad * 8];
#pragma unroll
    for (int si = 0; si < 4; ++si) {
      short8 ai = *(const short8*)&As[(wi * 64 + si * 16 + m16) * 32 + quad * 8];
#pragma unroll
      for (int sj = 0; sj < 2; ++sj)
        acc[si][sj] = __builtin_amdgcn_mfma_f32_16x16x32_bf16(
            ai, bj[sj], acc[si][sj], 0, 0, 0);
    }
  }
  const float al = ACT ? alpha_p[0] : 0.f;
  float ssq[4][4] = {};
#pragma unroll
  for (int si = 0; si < 4; ++si)
#pragma unroll
    for (int sj = 0; sj < 2; ++sj) {
      const int col = j0 + wj * 32 + sj * 16 + m16;
      const float bv = bias[col];
#pragma unroll
      for (int r = 0; r < 4; ++r) {
        const int row = i0 + wi * 64 + si * 16 + quad * 4 + r;
        float x = acc[si][sj][r] + bv;
        if (ACT) x = (x >= 0.f) ? x : al * x;
        const u16 xb = f2bf(x);
        ob[(size_t)row * DD + col] = xb;
        if (NRM) {
          const float xf = bf2f(xb);
          ssq[si][r] += xf * xf;
        }
      }
    }
  if (NRM) {
#pragma unroll
    for (int si = 0; si < 4; ++si)
#pragma unroll
      for (int r = 0; r < 4; ++r) {
        float s = ssq[si][r];
        s += __shfl_xor(s, 1, 64);
        s += __shfl_xor(s, 2, 64);
        s += __shfl_xor(s, 4, 64);
        s += __shfl_xor(s, 8, 64);
        if (m16 == 0)
          atomicAdd(&npan[i0 + wi * 64 + si * 16 + quad * 4 + r], s);
      }
  }
}

// ---- fused similarity, low-register: tile 128(i)x64(j), 512 thr (8 waves) ---
// wave = (ig = w&3: 32-row group) x (jh = w>>2: 32-col half); 32x32 per product
// -> 48 acc VGPRs/thread so 2 blocks (16 waves) can be CU-resident.
// zb: [r11s, r11m, r12s, r12m, c12s, c12m, c22s, c22m] x NN.
__global__ __launch_bounds__(512) void sim_half(
    const u16* __restrict__ na, const u16* __restrict__ nb,
    const float* __restrict__ n2A, const float* __restrict__ n2B,
    const int* __restrict__ mask, float* __restrict__ zb) {
  // panels: rows [0,128) na@I | [128,256) nb@I | [256,320) na@J | [320,384) nb@J
  __shared__ __align__(16) u16 sS[2][384 * 32];  // 48 KiB
  const int tid = threadIdx.x, w = tid >> 6, lane = tid & 63;
  const int rq = lane >> 2, cq = (lane & 3) * 8;
  const int quad = lane >> 4, m16 = lane & 15;
  const int ig = w & 3, jh = w >> 2;
  const int i0 = blockIdx.y * 128, j0 = blockIdx.x * 64;
  // staging role: p = w>>1 (panel), each pair of waves splits the panel rows
  const int p = w >> 1;
  const bool big = (p < 2);                       // 128-row panels
  const int nrows = big ? 64 : 32;                // rows this wave stages
  const int sub = (w & 1) * nrows;
  const int loff = (big ? p * 128 : 256 + (p - 2) * 64) + sub;
  const u16* gs = (p & 1) ? nb : na;
  const int gr0 = (big ? i0 : j0) + sub + rq;
  u16* lb0 = &sS[0][loff * 32];
  u16* lb1 = &sS[1][loff * 32];
#pragma unroll
  for (int rr = 0; rr < 64; rr += 16)
    if (rr < nrows) gld16(&gs[(size_t)(gr0 + rr) * DD + cq], lb0 + rr * 32);
  f32x4 a11[2][2] = {}, a12[2][2] = {}, a22[2][2] = {};
  for (int kc = 0; kc < 16; ++kc) {
    __syncthreads();
    if (kc < 15) {
      const int kn = (kc + 1) * 32;
      u16* d = (kc & 1) ? lb0 : lb1;
#pragma unroll
      for (int rr = 0; rr < 64; rr += 16)
        if (rr < nrows) gld16(&gs[(size_t)(gr0 + rr) * DD + kn + cq], d + rr * 32);
    }
    const u16* S = sS[kc & 1];
    short8 ai[2], bi[2], aj[2], bj[2];
#pragma unroll
    for (int s = 0; s < 2; ++s) {
      ai[s] = *(const short8*)&S[(ig * 32 + s * 16 + m16) * 32 + quad * 8];
      bi[s] = *(const short8*)&S[(128 + ig * 32 + s * 16 + m16) * 32 + quad * 8];
      aj[s] = *(const short8*)&S[(256 + jh * 32 + s * 16 + m16) * 32 + quad * 8];
      bj[s] = *(const short8*)&S[(320 + jh * 32 + s * 16 + m16) * 32 + quad * 8];
    }
#pragma unroll
    for (int si = 0; si < 2; ++si)
#pragma unroll
      for (int sj = 0; sj < 2; ++sj) {
        a11[si][sj] = __builtin_amdgcn_mfma_f32_16x16x32_bf16(ai[si], aj[sj], a11[si][sj], 0, 0, 0);
        a12[si][sj] = __builtin_amdgcn_mfma_f32_16x16x32_bf16(ai[si], bj[sj], a12[si][sj], 0, 0, 0);
        a22[si][sj] = __builtin_amdgcn_mfma_f32_16x16x32_bf16(bi[si], bj[sj], a22[si][sj], 0, 0, 0);
      }
  }
  __syncthreads();
  // overlay sS[0]: rred [4][128] + cred [4][64] = 768 floats
  float* rred = (float*)&sS[0][0];
  float* cred = rred + 512;
  for (int t = tid; t < 768; t += 512) rred[t] = 0.f;
  __syncthreads();
  // norm factors
  float iAr[2][4], iBr[2][4], iAc[2], iBc[2];
#pragma unroll
  for (int s = 0; s < 2; ++s) {
    const int ri = i0 + ig * 32 + s * 16 + quad * 4;
    float4 a4 = *(const float4*)&n2A[ri];
    float4 b4 = *(const float4*)&n2B[ri];
    iAr[s][0] = invnorm(a4.x); iAr[s][1] = invnorm(a4.y);
    iAr[s][2] = invnorm(a4.z); iAr[s][3] = invnorm(a4.w);
    iBr[s][0] = invnorm(b4.x); iBr[s][1] = invnorm(b4.y);
    iBr[s][2] = invnorm(b4.z); iBr[s][3] = invnorm(b4.w);
    iAc[s] = invnorm(n2A[j0 + jh * 32 + s * 16 + m16]);
    iBc[s] = invnorm(n2B[j0 + jh * 32 + s * 16 + m16]);
  }
  float cs12[2] = {}, cm12[2] = {}, cs22[2] = {}, cm22[2] = {};
#pragma unroll
  for (int si = 0; si < 2; ++si) {
    float rs11[4] = {}, rm11[4] = {}, rs12[4] = {}, rm12[4] = {};
    const int il0 = ig * 32 + si * 16 + quad * 4;
#pragma unroll
    for (int sj = 0; sj < 2; ++sj) {
      const int gj = j0 + jh * 32 + sj * 16 + m16;
#pragma unroll
      for (int r = 0; r < 4; ++r) {
        const float mv = (float)mask[(size_t)(i0 + il0 + r) * NN + gj];
        const float e11 = __expf(a11[si][sj][r] * iAr[si][r] * iAc[sj] * INV_TAU);
        const float e12 = __expf(a12[si][sj][r] * iAr[si][r] * iBc[sj] * INV_TAU);
        const float e22 = __expf(a22[si][sj][r] * iBr[si][r] * iBc[sj] * INV_TAU);
        rs11[r] += e11; rm11[r] += e11 * mv;
        rs12[r] += e12; rm12[r] += e12 * mv;
        cs12[sj] += e12; cm12[sj] += e12 * mv;
        cs22[sj] += e22; cm22[sj] += e22 * mv;
      }
    }
#pragma unroll
    for (int r = 0; r < 4; ++r) {
      float v0 = rs11[r], v1 = rm11[r], v2 = rs12[r], v3 = rm12[r];
#pragma unroll
      for (int o = 1; o < 16; o <<= 1) {
        v0 += __shfl_xor(v0, o, 64); v1 += __shfl_xor(v1, o, 64);
        v2 += __shfl_xor(v2, o, 64); v3 += __shfl_xor(v3, o, 64);
      }
      if (m16 == 0) {
        const int il = il0 + r;
        atomicAdd(&rred[0 * 128 + il], v0);
        atomicAdd(&rred[1 * 128 + il], v1);
        atomicAdd(&rred[2 * 128 + il], v2);
        atomicAdd(&rred[3 * 128 + il], v3);
      }
    }
  }
#pragma unroll
  for (int sj = 0; sj < 2; ++sj) {
    float v0 = cs12[sj], v1 = cm12[sj], v2 = cs22[sj], v3 = cm22[sj];
    v0 += __shfl_xor(v0, 16, 64); v0 += __shfl_xor(v0, 32, 64);
    v1 += __shfl_xor(v1, 16, 64); v1 += __shfl_xor(v1, 32, 64);
    v2 += __shfl_xor(v2, 16, 64); v2 += __shfl_xor(v2, 32, 64);
    v3 += __shfl_xor(v3, 16, 64); v3 += __shfl_xor(v3, 32, 64);
    if (lane < 16) {
      const int jl = jh * 32 + sj * 16 + lane;
      atomicAdd(&cred[0 * 64 + jl], v0);
      atomicAdd(&cred[1 * 64 + jl], v1);
      atomicAdd(&cred[2 * 64 + jl], v2);
      atomicAdd(&cred[3 * 64 + jl], v3);
    }
  }
  __syncthreads();
  if (tid < 128) {
#pragma unroll
    for (int q = 0; q < 4; ++q)
      atomicAdd(&zb[q * NN + i0 + tid], rred[q * 128 + tid]);
  } else if (tid < 192) {
    const int jl = tid - 128;
#pragma unroll
    for (int q = 0; q < 4; ++q)
      atomicAdd(&zb[(4 + q) * NN + j0 + jl], cred[q * 64 + jl]);
  }
}

// ---------------- paired D x D matvec, one wave per output row ---------------
__global__ __launch_bounds__(256) void matvec2(
    const float* __restrict__ M, const float* __restrict__ x1,
    const float* __restrict__ x2, const float* __restrict__ bias,
    const float* __restrict__ alpha_p, int act, float* __restrict__ y1,
    float* __restrict__ y2) {
  const float* x = blockIdx.y ? x2 : x1;
  float* y = blockIdx.y ? y2 : y1;
  const int row = (blockIdx.x * 256 + threadIdx.x) >> 6;
  const int lane = threadIdx.x & 63;
  float acc = 0.f;
#pragma unroll
  for (int t = 0; t < 8; ++t)
    acc = fmaf(M[(size_t)row * DD + lane + 64 * t], x[lane + 64 * t], acc);
  acc = wave_sum(acc);
  if (lane == 0) {
    if (bias) acc += bias[row];
    if (act) { const float al = alpha_p[0]; acc = (acc >= 0.f) ? acc : al * acc; }
    y[row] = acc;
  }
}

// ------- finalize: logsig (512 blocks) + local_fin (16 blocks) + combine -----
__global__ __launch_bounds__(256) void finalize(
    const float* __restrict__ zb, const u16* __restrict__ zb16,
    const float* __restrict__ sm1, const float* __restrict__ sm2,
    float* __restrict__ scal, float* __restrict__ out) {
  const int b = blockIdx.x;
  const int tid = threadIdx.x;
  if (b < 512) {
    const int ch = b >> 8, sub = b & 255;
    const u16* z = zb16 + (size_t)ch * ((size_t)NN * DD);
    const float* sp = ch ? sm2 : sm1;
    const float* sn = ch ? sm1 : sm2;
    const int lane = tid & 63, wv = tid >> 6;
    float sp8[8], sn8[8];
#pragma unroll
    for (int k = 0; k < 8; ++k) {
      sp8[k] = sp[lane * 8 + k];
      sn8[k] = sn[lane * 8 + k];
    }
    float accP = 0.f, accN = 0.f;
#pragma unroll
    for (int rr = 0; rr < 4; ++rr) {
      const int row = sub * 16 + wv * 4 + rr;
      short8 v = *(const short8*)&z[(size_t)row * DD + lane * 8];
      float dp = 0.f, dn = 0.f;
#pragma unroll
      for (int k = 0; k < 8; ++k) {
        const float f = bf2f(((const u16*)&v)[k]);
        dp = fmaf(f, sp8[k], dp);
        dn = fmaf(f, sn8[k], dn);
      }
      dp = wave_sum(dp);
      dn = wave_sum(dn);
      if (lane == 0) {
        accP += -logf(1.f / (1.f + __expf(-dp)) + EPSV);
        accN += -logf(1.f - 1.f / (1.f + __expf(-dn)) + EPSV);
      }
    }
    if (lane == 0) {
      atomicAdd(&scal[ch ? 4 : 2], accP);
      atomicAdd(&scal[ch ? 3 : 5], accN);
    }
  } else {
    const int i = (b - 512) * 256 + tid;
    const float r11 = zb[i], r11m = zb[NN + i];
    const float r12 = zb[2 * NN + i], r12m = zb[3 * NN + i];
    const float c12 = zb[4 * NN + i], c12m = zb[5 * NN + i];
    const float c22 = zb[6 * NN + i], c22m = zb[7 * NN + i];
    float l1 = -logf(r12m / (r11 + r12 - r11m));
    float l2 = -logf(c12m / (c22 + c12 - c22m));
    l1 = wave_sum(l1);
    l2 = wave_sum(l2);
    __shared__ float b1[4], b2[4];
    const int lane = tid & 63, wid = tid >> 6;
    if (lane == 0) { b1[wid] = l1; b2[wid] = l2; }
    __syncthreads();
    if (tid == 0) {
      atomicAdd(&scal[0], b1[0] + b1[1] + b1[2] + b1[3]);
      atomicAdd(&scal[1], b2[0] + b2[1] + b2[2] + b2[3]);
    }
  }
  __syncthreads();
  if (tid == 0) {
    unsigned int* cnt = (unsigned int*)&scal[8];
    const unsigned old = atomicAdd(cnt, 1u);
    if (old == (unsigned)(gridDim.x - 1)) {
      const float s0 = atomicAdd(&scal[0], 0.f);
      const float s1 = atomicAdd(&scal[1], 0.f);
      const float p1 = atomicAdd(&scal[2], 0.f);
      const float n1 = atomicAdd(&scal[3], 0.f);
      const float p2 = atomicAdd(&scal[4], 0.f);
      const float n2 = atomicAdd(&scal[5], 0.f);
      const float local = 0.5f * (s0 + s1) * (1.f / NN);
      const float glob = 0.25f * (p1 + n1 + p2 + n2) * (1.f / NN);
      out[0] = 0.5f * local + 0.5f * glob;
    }
  }
}

extern "C" void kernel_launch(void* const* d_in, const int* in_sizes, int n_in,
                              void* d_out, int out_size, void* d_ws,
                              size_t ws_size, hipStream_t stream) {
  const float* z1 = (const float*)d_in[0];
  const float* z2 = (const float*)d_in[1];
  const float* lw1 = (const float*)d_in[2];
  const float* lb1 = (const float*)d_in[3];
  const float* la = (const float*)d_in[4];
  const float* lw2 = (const float*)d_in[5];
  const float* lb2 = (const float*)d_in[6];
  const float* gw1 = (const float*)d_in[7];
  const float* gb1 = (const float*)d_in[8];
  const float* ga = (const float*)d_in[9];
  const float* gw2 = (const float*)d_in[10];
  const float* gb2 = (const float*)d_in[11];
  const float* W = (const float*)d_in[12];
  const int* mask = (const int*)d_in[13];
  float* out = (float*)d_out;

  const size_t ND = (size_t)NN * DD;
  u16* W1b = (u16*)d_ws;
  u16* W2b = W1b + 512 * 512;
  u16* Ab = W1b + 2 * 512 * 512;
  u16* Pb = Ab + 2 * ND;
  u16* Hb = Pb + 2 * ND;
  float* zbf = (float*)(Hb + 2 * ND);     // 8*NN (zeroed by prep y2)
  float* norm2 = zbf + 8 * NN;            // 2*NN (zeroed by prep y2)
  float* s1 = norm2 + 2 * NN;             // memset region start
  float* s2 = s1 + DD;
  float* scal = s2 + DD;                  // [16], counter at [8]
  float* summ1 = scal + 16;
  float* summ2 = summ1 + DD;
  float* t1 = summ2 + DD;
  float* t2 = t1 + DD;
  float* hg1 = t2 + DD;
  float* hg2 = hg1 + DD;

  hipMemsetAsync(s1, 0, (2 * DD + 16) * sizeof(float), stream);

  dim3 blk(256);
  prep<<<dim3(64, 3), blk, 0, stream>>>(z1, z2, lw1, lw2, Ab, W1b, s1, s2, zbf);

  dim3 gg(8, 32, 2);
  gemm_mfma<1, 0><<<gg, blk, 0, stream>>>(Ab, W1b, lb1, la, Pb, nullptr);
  gemm_mfma<0, 1><<<gg, blk, 0, stream>>>(Pb, W2b, lb2, la, Hb, norm2);

  sim_half<<<dim3(NN / 64, NN / 128), dim3(512), 0, stream>>>(
      Hb, Hb + ND, norm2, norm2 + NN, mask, zbf);

  matvec2<<<dim3(DD / 4, 2), blk, 0, stream>>>(gw1, s1, s2, gb1, ga, 1, t1, t2);
  matvec2<<<dim3(DD / 4, 2), blk, 0, stream>>>(gw2, t1, t2, gb2, nullptr, 0, hg1, hg2);
  matvec2<<<dim3(DD / 4, 2), blk, 0, stream>>>(W, hg1, hg2, nullptr, nullptr, 0, summ1, summ2);

  finalize<<<528, blk, 0, stream>>>(zbf, Ab, summ1, summ2, scal, out);
}